// Round 3
// baseline (1434.133 us; speedup 1.0000x reference)
//
#include <hip/hip_runtime.h>
#include <cstdint>
#include <cstddef>

#define CC   96
#define BB   32
#define HHn  112
#define WWn  112
#define HWn  (HHn*WWn)        // 12544
#define NPIX (BB*HWn)         // 401408
#define EPSf 1e-5f

#define HSTR 28               // halo row stride in words (b128-aligned, 2-way banks)
#define HCH  (22*HSTR)        // 616 words per channel halo
#define NCHG 8                // channels per iteration
#define NGRP (CC/NCHG)        // 12 iterations
#define NSLOT 16              // staging slots per thread: 8*484=3872 elems / 256 thr

// ---------------- w_mix transpose: wT[c*96+o] = w[o*96+c] ----------------
__global__ __launch_bounds__(256) void k_transpose(const float* __restrict__ w,
                                                   float* __restrict__ wT) {
  int i = blockIdx.x * 256 + threadIdx.x;
  if (i < CC * CC) {
    int o = i / CC, c = i % CC;
    wT[c * CC + o] = w[i];
  }
}

// ------- fused depthwise 7x7 conv + 1x1 mix + BN stats (per-block partials) -------
// Block = 16x16 pixel tile of one image; 256 threads, 4 waves.
// Per iteration (8 channels): each half-wave owns one channel, each lane a 2x4
// output strip (3x ds_read_b128 per row, 8 rows). Conv results go through
// f_lds to the mix phase where each thread owns 1 pixel x 96 out-channels
// (acc[96] in VGPRs). Halo single-buffered (stride 28), staged loads issued at
// iter start, LDS-written between the two barriers. Bias dropped (BN cancels).
__global__ __launch_bounds__(256, 2) void k_fused(const float* __restrict__ x,
                                                  const float* __restrict__ hk,
                                                  const float* __restrict__ wT,
                                                  float* __restrict__ mixed,
                                                  float* __restrict__ ssum,
                                                  float* __restrict__ ssq) {
  __shared__ float halo[NCHG * HCH];   // 4928 floats = 19712 B
  __shared__ float flds[NCHG * 256];   // 2048 floats = 8192 B (also stats scratch)

  int bid = blockIdx.x;
  int logical = (bid & 7) * 196 + (bid >> 3);   // 1568 = 8*196, bijective
  int b  = logical / 49;
  int t  = logical % 49;
  int h0 = (t / 7) * 16, w0 = (t % 7) * 16;

  int tid  = threadIdx.x;
  int lane = tid & 63;
  int w_id = __builtin_amdgcn_readfirstlane(tid >> 6);   // wave id 0..3 (uniform)
  int hB   = (lane >> 5) & 1;                            // half-wave -> channel parity
  int sid  = lane & 31;
  int r0   = (sid >> 2) * 2;                             // strip row 0..14 even
  int pw0  = (sid & 3) * 4;                              // strip col 0,4,8,12
  int cloc = 2 * w_id + hB;                              // local channel 0..7

  const float* xb = x + (long)b * CC * HWn;

  // ---- staging slot precompute (constant across iterations) ----
  int base32[NSLOT];     // c*HW + row*W + col (clamped to 0 when OOB)
  int ldsw[NSLOT];       // halo word address
  unsigned okm = 0;
#pragma unroll
  for (int s = 0; s < NSLOT; ++s) {
    int idx = tid + 256 * s;
    if (s < 15 || tid < (NCHG * 484 - 15 * 256)) {   // idx < 3872
      int c = idx / 484, rem = idx % 484;
      int r = rem / 22, col = rem % 22;
      int gr = h0 - 3 + r, gc = w0 - 3 + col;
      bool ok = ((unsigned)gr < HHn) && ((unsigned)gc < WWn);
      if (ok) okm |= 1u << s;
      base32[s] = ok ? (c * HWn + gr * WWn + gc) : 0;
      ldsw[s]   = c * HCH + r * HSTR + col;
    } else {
      base32[s] = 0; ldsw[s] = 0;
    }
  }

  float acc[CC];
#pragma unroll
  for (int o = 0; o < CC; ++o) acc[o] = 0.f;

  // ---- prologue: stage channels 0..7 ----
  {
    float sv[NSLOT];
#pragma unroll
    for (int s = 0; s < NSLOT; ++s)
      sv[s] = (okm >> s & 1u) ? xb[base32[s]] : 0.f;
#pragma unroll
    for (int s = 0; s < NSLOT; ++s)
      if (s < 15 || tid < (NCHG * 484 - 15 * 256)) halo[ldsw[s]] = sv[s];
  }
  __syncthreads();

  const float4* h4 = (const float4*)halo;

  for (int g = 0; g < NGRP; ++g) {
    int cb = g * NCHG;

    // issue next group's staged loads early (hidden under conv)
    float sv[NSLOT];
    if (g + 1 < NGRP) {
      int coff = (cb + NCHG) * HWn;
#pragma unroll
      for (int s = 0; s < NSLOT; ++s)
        sv[s] = (okm >> s & 1u) ? xb[coff + base32[s]] : 0.f;
    }

    // ---- conv: 2x4 strip, channel cb+cloc ----
    const float* hkA = hk + (cb + 2 * w_id) * 49;   // wave-uniform -> s_loads
    const float* hkB = hkA + 49;
    float f[8];
#pragma unroll
    for (int i = 0; i < 8; ++i) f[i] = 0.f;

    int hb = cloc * HCH + r0 * HSTR + pw0;
#pragma unroll
    for (int rr = 0; rr < 8; ++rr) {
      int a4 = (hb + rr * HSTR) >> 2;
      float4 va = h4[a4], vb = h4[a4 + 1], vc = h4[a4 + 2];
      float rw[12];
      rw[0] = va.x; rw[1] = va.y; rw[2]  = va.z; rw[3]  = va.w;
      rw[4] = vb.x; rw[5] = vb.y; rw[6]  = vb.z; rw[7]  = vb.w;
      rw[8] = vc.x; rw[9] = vc.y; rw[10] = vc.z; rw[11] = vc.w;
      if (rr < 7) {               // contributes to output row r0 (kh = rr)
#pragma unroll
        for (int kw = 0; kw < 7; ++kw) {
          float wv = hB ? hkB[rr * 7 + kw] : hkA[rr * 7 + kw];
          f[0] = fmaf(rw[kw + 0], wv, f[0]);
          f[1] = fmaf(rw[kw + 1], wv, f[1]);
          f[2] = fmaf(rw[kw + 2], wv, f[2]);
          f[3] = fmaf(rw[kw + 3], wv, f[3]);
        }
      }
      if (rr >= 1) {              // output row r0+1 (kh = rr-1)
#pragma unroll
        for (int kw = 0; kw < 7; ++kw) {
          float wv = hB ? hkB[(rr - 1) * 7 + kw] : hkA[(rr - 1) * 7 + kw];
          f[4] = fmaf(rw[kw + 0], wv, f[4]);
          f[5] = fmaf(rw[kw + 1], wv, f[5]);
          f[6] = fmaf(rw[kw + 2], wv, f[6]);
          f[7] = fmaf(rw[kw + 3], wv, f[7]);
        }
      }
    }
    {
      float4 fa; fa.x = f[0]; fa.y = f[1]; fa.z = f[2]; fa.w = f[3];
      float4 fb; fb.x = f[4]; fb.y = f[5]; fb.z = f[6]; fb.w = f[7];
      ((float4*)flds)[(cloc * 256 + r0 * 16 + pw0) >> 2]       = fa;
      ((float4*)flds)[(cloc * 256 + (r0 + 1) * 16 + pw0) >> 2] = fb;
    }
    __syncthreads();

    // ---- write staged halo for next group (overwrites buffer just consumed) ----
    if (g + 1 < NGRP) {
#pragma unroll
      for (int s = 0; s < NSLOT; ++s)
        if (s < 15 || tid < (NCHG * 484 - 15 * 256)) halo[ldsw[s]] = sv[s];
    }

    // ---- mix: this thread's pixel, 8 channels x 96 out ----
    float fc[NCHG];
#pragma unroll
    for (int c8 = 0; c8 < NCHG; ++c8) fc[c8] = flds[c8 * 256 + tid];
#pragma unroll
    for (int c8 = 0; c8 < NCHG; ++c8) {
      const float* wc = wT + (cb + c8) * CC;   // wave-uniform -> s_loads
#pragma unroll
      for (int o = 0; o < CC; ++o) acc[o] = fmaf(fc[c8], wc[o], acc[o]);
    }
    __syncthreads();
  }

  // ---- store mixed (coalesced per 16-thread row) ----
  float* mb = mixed + (long)b * CC * HWn + (long)(h0 + (tid >> 4)) * WWn + (w0 + (tid & 15));
#pragma unroll
  for (int o = 0; o < CC; ++o) mb[(long)o * HWn] = acc[o];

  // ---- fused BN stats: block partials -> global atomics ----
  float* part = flds;   // reuse (768 floats needed <= 2048)
#pragma unroll
  for (int o = 0; o < CC; ++o) {
    float s = acc[o];
    float q = acc[o] * acc[o];
#pragma unroll
    for (int m = 1; m <= 32; m <<= 1) {
      s += __shfl_xor(s, m);
      q += __shfl_xor(q, m);
    }
    if (lane == 0) {
      part[w_id * 192 + o]      = s;
      part[w_id * 192 + 96 + o] = q;
    }
  }
  __syncthreads();
  if (tid < CC) {
    float s = part[tid] + part[192 + tid] + part[384 + tid] + part[576 + tid];
    atomicAdd(&ssum[tid], s);
  } else if (tid >= 128 && tid < 128 + CC) {
    int o = tid - 128;
    float q = part[96 + o] + part[288 + o] + part[480 + o] + part[672 + o];
    atomicAdd(&ssq[o], q);
  }
}

__global__ void k_finalize(const float* __restrict__ ssum,
                           const float* __restrict__ ssq,
                           float* __restrict__ meanv,
                           float* __restrict__ rstdv) {
  int o = threadIdx.x;
  if (o < CC) {
    float m = ssum[o] * (1.0f / NPIX);
    float v = ssq[o] * (1.0f / NPIX) - m * m;
    meanv[o] = m;
    rstdv[o] = 1.0f / sqrtf(v + EPSf);
  }
}

// ---------------- BN (affine=False) + exact GELU ----------------
__global__ __launch_bounds__(256) void k_bngelu(const float* __restrict__ mixed,
                                                const float* __restrict__ meanv,
                                                const float* __restrict__ rstdv,
                                                float* __restrict__ out) {
  long i4 = (long)blockIdx.x * 256 + threadIdx.x;
  long e = i4 * 4;
  int o = (int)((e / HWn) % CC);       // all 4 elems in same channel plane
  float m = meanv[o], r = rstdv[o];
  float4 v = *(const float4*)(mixed + e);
  float4 g;
  float z;
  z = (v.x - m) * r; g.x = 0.5f * z * (1.0f + erff(z * 0.70710678118654752f));
  z = (v.y - m) * r; g.y = 0.5f * z * (1.0f + erff(z * 0.70710678118654752f));
  z = (v.z - m) * r; g.z = 0.5f * z * (1.0f + erff(z * 0.70710678118654752f));
  z = (v.w - m) * r; g.w = 0.5f * z * (1.0f + erff(z * 0.70710678118654752f));
  *(float4*)(out + e) = g;
}

extern "C" void kernel_launch(void* const* d_in, const int* in_sizes, int n_in,
                              void* d_out, int out_size, void* d_ws, size_t ws_size,
                              hipStream_t stream) {
  const float* hk   = (const float*)d_in[0];   // local_hk [96,1,7,7]
  const float* x    = (const float*)d_in[1];   // x [32,96,112,112]
  const float* wmix = (const float*)d_in[2];   // w_mix [96,96]
  const float* bmix = (const float*)d_in[3];   // b_mix [96] (cancels in BN)
  (void)bmix;
  float* out = (float*)d_out;

  char* ws = (char*)d_ws;
  float* stats = (float*)ws;                   // sum[96], ssq[96], mean[96], rstd[96]
  float* wT    = (float*)(ws + 2048);          // 96*96 floats
  float* mixed = (float*)(ws + 40960);         // 38,535,168 floats (154 MB)

  hipMemsetAsync(stats, 0, 768, stream);       // zero sum+ssq each call

  k_transpose<<<36, 256, 0, stream>>>(wmix, wT);
  k_fused<<<1568, 256, 0, stream>>>(x, hk, wT, mixed, stats, stats + 96);
  k_finalize<<<1, 128, 0, stream>>>(stats, stats + 96, stats + 192, stats + 288);
  k_bngelu<<<37632, 256, 0, stream>>>(mixed, stats + 192, stats + 288, out);
}

// Round 4
// 327.602 us; speedup vs baseline: 4.3777x; 4.3777x over previous
//
#include <hip/hip_runtime.h>
#include <cstdint>
#include <cstddef>

#define CC   96
#define BB   32
#define HHn  112
#define WWn  112
#define HWn  (HHn*WWn)        // 12544
#define NPIX (BB*HWn)         // 401408
#define EPSf 1e-5f

// ---------------- w_mix transpose: wT[c*96+o] = w[o*96+c] ----------------
__global__ __launch_bounds__(256) void k_transpose(const float* __restrict__ w,
                                                   float* __restrict__ wT) {
  int i = blockIdx.x * 256 + threadIdx.x;
  if (i < CC * CC) {
    int o = i / CC, c = i % CC;
    wT[c * CC + o] = w[i];
  }
}

// ---------------- depthwise 7x7 conv, streaming-row register version ----------
// One wave per (b,c) plane; weights in SGPRs (readfirstlane-forced). Each lane
// owns an 8-wide x 28-tall output column chunk (lane = q*16+s; s<14 active).
// Input rows stream once through a 14-float register window; 7 rolling 8-wide
// accumulators, statically indexed via a 7-phase unrolled loop (no scratch).
__global__ __launch_bounds__(256) void k_conv(const float* __restrict__ x,
                                              const float* __restrict__ hk,
                                              float* __restrict__ feat) {
  int tid = threadIdx.x;
  int wid = __builtin_amdgcn_readfirstlane(tid >> 6);          // wave 0..3
  int plane = __builtin_amdgcn_readfirstlane(blockIdx.x * 4 + wid);
  int c = plane % CC;
  const float* xp = x + (long)plane * HWn;
  float* fp = feat + (long)plane * HWn;

  // 49 weights -> SGPRs (uniform per wave)
  float wk[49];
  const float* kc = hk + c * 49;
#pragma unroll
  for (int i = 0; i < 49; ++i)
    wk[i] = __uint_as_float(__builtin_amdgcn_readfirstlane(__float_as_uint(kc[i])));

  int lane = tid & 63;
  int q = lane >> 4;              // h-chunk 0..3 (28 rows each)
  int s = lane & 15;              // w-strip; active if s<14
  bool active = (s < 14);
  int cb = active ? s * 8 : 0;    // col base, window cols cb-3..cb+10
  int qb = q * 28;
  bool aok0 = active && (s > 0);
  bool dok0 = (s < 13);
  int offA = aok0 ? cb - 4 : cb;  // clamped, always in-bounds
  int offD = dok0 ? cb + 8 : cb;

  float acc[7][8];
#pragma unroll
  for (int i = 0; i < 7; ++i)
#pragma unroll
    for (int j = 0; j < 8; ++j) acc[i][j] = 0.f;

  for (int blk = 0; blk < 5; ++blk) {
#pragma unroll
    for (int ph = 0; ph < 7; ++ph) {
      int rr = blk * 7 + ph;            // streamed input-row index 0..34
      int r = qb + rr - 3;              // global input row (per-lane)
      bool vok = (rr < 34) && ((unsigned)r < (unsigned)HHn);
      int rc = r < 0 ? 0 : (r > HHn - 1 ? HHn - 1 : r);
      const float* row = xp + rc * WWn;
      float4 A  = *(const float4*)(row + offA);
      float4 Bv = *(const float4*)(row + cb);
      float4 Cv = *(const float4*)(row + cb + 4);
      float4 D  = *(const float4*)(row + offD);
      bool aok = vok && aok0;
      bool dok = vok && dok0;
      float win[15];
      win[0]  = 0.f;                    // unused
      win[1]  = aok ? A.y : 0.f;
      win[2]  = aok ? A.z : 0.f;
      win[3]  = aok ? A.w : 0.f;
      win[4]  = vok ? Bv.x : 0.f;
      win[5]  = vok ? Bv.y : 0.f;
      win[6]  = vok ? Bv.z : 0.f;
      win[7]  = vok ? Bv.w : 0.f;
      win[8]  = vok ? Cv.x : 0.f;
      win[9]  = vok ? Cv.y : 0.f;
      win[10] = vok ? Cv.z : 0.f;
      win[11] = vok ? Cv.w : 0.f;
      win[12] = dok ? D.x : 0.f;
      win[13] = dok ? D.y : 0.f;
      win[14] = dok ? D.z : 0.f;

      // input row rr feeds output rows orel = rr-kh (slot static per ph,kh)
#pragma unroll
      for (int kh = 0; kh < 7; ++kh) {
        if (rr >= kh && rr - kh <= 27) {         // wave-uniform branch
          const int slot = ((ph - kh) % 7 + 7) % 7;
#pragma unroll
          for (int kw = 0; kw < 7; ++kw) {
            float wv = wk[kh * 7 + kw];
#pragma unroll
            for (int j = 0; j < 8; ++j)
              acc[slot][j] = fmaf(win[j + kw + 1], wv, acc[slot][j]);
          }
        }
      }

      // output row orel = rr-6 is complete -> store & reset its slot
      if (rr >= 6 && rr < 34) {
        const int slot = (ph + 1) % 7;
        if (active) {
          float* orow = fp + (qb + rr - 6) * WWn + cb;
          float4 o1, o2;
          o1.x = acc[slot][0]; o1.y = acc[slot][1];
          o1.z = acc[slot][2]; o1.w = acc[slot][3];
          o2.x = acc[slot][4]; o2.y = acc[slot][5];
          o2.z = acc[slot][6]; o2.w = acc[slot][7];
          *(float4*)orow       = o1;
          *(float4*)(orow + 4) = o2;
        }
#pragma unroll
        for (int j = 0; j < 8; ++j) acc[slot][j] = 0.f;
      }
    }
  }
}

// ---------------- 1x1 mix: mixed[b,o,p] = sum_c feat[b,c,p]*w[o,c] ----------
// (bias dropped: BN(affine=False) cancels per-channel constant shifts)
__global__ __launch_bounds__(256) void k_mix(const float* __restrict__ feat,
                                             const float* __restrict__ wT,
                                             float* __restrict__ mixed) {
  int tid = threadIdx.x;
  int bid = blockIdx.x;                // b*49 + tile
  int b = bid / 49;
  int p = (bid % 49) * 256 + tid;      // pixel within image
  const float* fb = feat + (long)b * CC * HWn + p;

  float acc[CC];
#pragma unroll
  for (int o = 0; o < CC; ++o) acc[o] = 0.f;

  for (int c = 0; c < CC; ++c) {
    float f = fb[(long)c * HWn];
    const float* wc = wT + c * CC;     // wave-uniform -> scalar loads
#pragma unroll
    for (int o = 0; o < CC; ++o) acc[o] = fmaf(f, wc[o], acc[o]);
  }

  float* mb = mixed + (long)b * CC * HWn + p;
#pragma unroll
  for (int o = 0; o < CC; ++o) mb[(long)o * HWn] = acc[o];
}

// ---------------- per-channel sum / sumsq over (b,h,w) ----------------
__global__ __launch_bounds__(256) void k_stats(const float* __restrict__ mixed,
                                               float* __restrict__ ssum,
                                               float* __restrict__ ssq) {
  int b = blockIdx.x;   // 32
  int o = blockIdx.y;   // 96
  const float4* p4 = (const float4*)(mixed + ((long)b * CC + o) * HWn);
  float s = 0.f, q = 0.f;
  for (int i = threadIdx.x; i < HWn / 4; i += 256) {
    float4 v = p4[i];
    s += v.x + v.y + v.z + v.w;
    q += v.x * v.x + v.y * v.y + v.z * v.z + v.w * v.w;
  }
  __shared__ float ls[256], lq[256];
  ls[threadIdx.x] = s; lq[threadIdx.x] = q;
  __syncthreads();
  for (int st = 128; st > 0; st >>= 1) {
    if (threadIdx.x < st) {
      ls[threadIdx.x] += ls[threadIdx.x + st];
      lq[threadIdx.x] += lq[threadIdx.x + st];
    }
    __syncthreads();
  }
  if (threadIdx.x == 0) {
    atomicAdd(&ssum[o], ls[0]);
    atomicAdd(&ssq[o], lq[0]);
  }
}

__global__ void k_finalize(const float* __restrict__ ssum,
                           const float* __restrict__ ssq,
                           float* __restrict__ meanv,
                           float* __restrict__ rstdv) {
  int o = threadIdx.x;
  if (o < CC) {
    float m = ssum[o] * (1.0f / NPIX);
    float v = ssq[o] * (1.0f / NPIX) - m * m;
    meanv[o] = m;
    rstdv[o] = 1.0f / sqrtf(v + EPSf);
  }
}

// ---------------- BN (affine=False) + exact GELU ----------------
__global__ __launch_bounds__(256) void k_bngelu(const float* __restrict__ mixed,
                                                const float* __restrict__ meanv,
                                                const float* __restrict__ rstdv,
                                                float* __restrict__ out) {
  long i4 = (long)blockIdx.x * 256 + threadIdx.x;
  long e = i4 * 4;
  int o = (int)((e / HWn) % CC);       // all 4 elems in same channel plane
  float m = meanv[o], r = rstdv[o];
  float4 v = *(const float4*)(mixed + e);
  float4 g;
  float z;
  z = (v.x - m) * r; g.x = 0.5f * z * (1.0f + erff(z * 0.70710678118654752f));
  z = (v.y - m) * r; g.y = 0.5f * z * (1.0f + erff(z * 0.70710678118654752f));
  z = (v.z - m) * r; g.z = 0.5f * z * (1.0f + erff(z * 0.70710678118654752f));
  z = (v.w - m) * r; g.w = 0.5f * z * (1.0f + erff(z * 0.70710678118654752f));
  *(float4*)(out + e) = g;
}

extern "C" void kernel_launch(void* const* d_in, const int* in_sizes, int n_in,
                              void* d_out, int out_size, void* d_ws, size_t ws_size,
                              hipStream_t stream) {
  const float* hk   = (const float*)d_in[0];   // local_hk [96,1,7,7]
  const float* x    = (const float*)d_in[1];   // x [32,96,112,112]
  const float* wmix = (const float*)d_in[2];   // w_mix [96,96]
  const float* bmix = (const float*)d_in[3];   // b_mix [96] (cancels in BN)
  (void)bmix;
  float* out = (float*)d_out;

  char* ws = (char*)d_ws;
  float* stats = (float*)ws;                   // sum[96], ssq[96], mean[96], rstd[96]
  float* wT    = (float*)(ws + 2048);          // 96*96 floats
  float* mixed = (float*)(ws + 40960);         // 38,535,168 floats (154 MB)
  float* feat  = out;                          // reuse d_out as conv scratch

  hipMemsetAsync(stats, 0, 768, stream);       // zero sum+ssq each call

  k_transpose<<<36, 256, 0, stream>>>(wmix, wT);
  k_conv<<<768, 256, 0, stream>>>(x, hk, feat);
  k_mix<<<1568, 256, 0, stream>>>(feat, wT, mixed);
  k_stats<<<dim3(32, 96), 256, 0, stream>>>(mixed, stats, stats + 96);
  k_finalize<<<1, 128, 0, stream>>>(stats, stats + 96, stats + 192, stats + 288);
  k_bngelu<<<37632, 256, 0, stream>>>(mixed, stats + 192, stats + 288, out);
}

// Round 5
// 311.257 us; speedup vs baseline: 4.6075x; 1.0525x over previous
//
#include <hip/hip_runtime.h>
#include <cstdint>
#include <cstddef>

#define CC   96
#define BB   32
#define HHn  112
#define WWn  112
#define HWn  (HHn*WWn)        // 12544
#define NPIX (BB*HWn)         // 401408
#define EPSf 1e-5f

typedef __attribute__((ext_vector_type(8))) short bf16x8;
typedef __attribute__((ext_vector_type(4))) float f32x4;

__device__ inline unsigned short f2bf(float f) {      // RNE f32 -> bf16
  unsigned u = __float_as_uint(f);
  return (unsigned short)((u + 0x7FFFu + ((u >> 16) & 1u)) >> 16);
}
__device__ inline float bf2f(unsigned short h) {
  return __uint_as_float(((unsigned)h) << 16);
}

// ---------------- w_mix f32[o][c] -> bf16[o][c] ----------------
__global__ __launch_bounds__(256) void k_prep(const float* __restrict__ w,
                                              unsigned short* __restrict__ wbf) {
  int i = blockIdx.x * 256 + threadIdx.x;
  if (i < CC * CC) wbf[i] = f2bf(w[i]);
}

// ---------------- depthwise 7x7 conv, streaming-row, bf16 output ----------
__global__ __launch_bounds__(256) void k_conv(const float* __restrict__ x,
                                              const float* __restrict__ hk,
                                              unsigned short* __restrict__ feat) {
  int tid = threadIdx.x;
  int wid = __builtin_amdgcn_readfirstlane(tid >> 6);
  int plane = __builtin_amdgcn_readfirstlane(blockIdx.x * 4 + wid);
  int c = plane % CC;
  const float* xp = x + (long)plane * HWn;
  unsigned short* fp = feat + (long)plane * HWn;

  float wk[49];
  const float* kc = hk + c * 49;
#pragma unroll
  for (int i = 0; i < 49; ++i)
    wk[i] = __uint_as_float(__builtin_amdgcn_readfirstlane(__float_as_uint(kc[i])));

  int lane = tid & 63;
  int q = lane >> 4;
  int s = lane & 15;
  bool active = (s < 14);
  int cb = active ? s * 8 : 0;
  int qb = q * 28;
  bool aok0 = active && (s > 0);
  bool dok0 = (s < 13);
  int offA = aok0 ? cb - 4 : cb;
  int offD = dok0 ? cb + 8 : cb;

  float acc[7][8];
#pragma unroll
  for (int i = 0; i < 7; ++i)
#pragma unroll
    for (int j = 0; j < 8; ++j) acc[i][j] = 0.f;

  for (int blk = 0; blk < 5; ++blk) {
#pragma unroll
    for (int ph = 0; ph < 7; ++ph) {
      int rr = blk * 7 + ph;
      int r = qb + rr - 3;
      bool vok = (rr < 34) && ((unsigned)r < (unsigned)HHn);
      int rc = r < 0 ? 0 : (r > HHn - 1 ? HHn - 1 : r);
      const float* row = xp + rc * WWn;
      float4 A  = *(const float4*)(row + offA);
      float4 Bv = *(const float4*)(row + cb);
      float4 Cv = *(const float4*)(row + cb + 4);
      float4 D  = *(const float4*)(row + offD);
      bool aok = vok && aok0;
      bool dok = vok && dok0;
      float win[15];
      win[0]  = 0.f;
      win[1]  = aok ? A.y : 0.f;
      win[2]  = aok ? A.z : 0.f;
      win[3]  = aok ? A.w : 0.f;
      win[4]  = vok ? Bv.x : 0.f;
      win[5]  = vok ? Bv.y : 0.f;
      win[6]  = vok ? Bv.z : 0.f;
      win[7]  = vok ? Bv.w : 0.f;
      win[8]  = vok ? Cv.x : 0.f;
      win[9]  = vok ? Cv.y : 0.f;
      win[10] = vok ? Cv.z : 0.f;
      win[11] = vok ? Cv.w : 0.f;
      win[12] = dok ? D.x : 0.f;
      win[13] = dok ? D.y : 0.f;
      win[14] = dok ? D.z : 0.f;

#pragma unroll
      for (int kh = 0; kh < 7; ++kh) {
        if (rr >= kh && rr - kh <= 27) {
          const int slot = ((ph - kh) % 7 + 7) % 7;
#pragma unroll
          for (int kw = 0; kw < 7; ++kw) {
            float wv = wk[kh * 7 + kw];
#pragma unroll
            for (int j = 0; j < 8; ++j)
              acc[slot][j] = fmaf(win[j + kw + 1], wv, acc[slot][j]);
          }
        }
      }

      if (rr >= 6 && rr < 34) {
        const int slot = (ph + 1) % 7;
        if (active) {
          unsigned short* orow = fp + (qb + rr - 6) * WWn + cb;
          uint4 pk;
          pk.x = (unsigned)f2bf(acc[slot][0]) | ((unsigned)f2bf(acc[slot][1]) << 16);
          pk.y = (unsigned)f2bf(acc[slot][2]) | ((unsigned)f2bf(acc[slot][3]) << 16);
          pk.z = (unsigned)f2bf(acc[slot][4]) | ((unsigned)f2bf(acc[slot][5]) << 16);
          pk.w = (unsigned)f2bf(acc[slot][6]) | ((unsigned)f2bf(acc[slot][7]) << 16);
          *(uint4*)orow = pk;
        }
#pragma unroll
        for (int j = 0; j < 8; ++j) acc[slot][j] = 0.f;
      }
    }
  }
}

// ------- MFMA 1x1 mix (bf16) + fused BN stats -------
// Block = 64 pixels of one image; 4 waves x 16 pixels. Each wave computes all
// 96 out-channels: 6 M-tiles x 3 K-steps of mfma_f32_16x16x32_bf16.
// A (= w[o][c]) frags held in registers for the whole block. B (= feat[c][p])
// staged in LDS, XOR-swizzled so both u16 transpose-writes and b128 frag
// reads are <=2-way bank aliased (free). Stats reduced via shfl + LDS atomics.
__global__ __launch_bounds__(256) void k_mix(const unsigned short* __restrict__ feat,
                                             const unsigned short* __restrict__ wbf,
                                             unsigned short* __restrict__ mixed,
                                             float* __restrict__ ssum,
                                             float* __restrict__ ssq) {
  __shared__ unsigned short flds[64 * 128];   // 16 KB, halfword addressed
  __shared__ float lsum[CC], lsq[CC];

  int tid = threadIdx.x;
  int bid = blockIdx.x;
  int b = bid / 196, tile = bid % 196;
  int p0t = tile * 64;

  if (tid < CC) { lsum[tid] = 0.f; lsq[tid] = 0.f; }

  // ---- stage feat tile [96 c][64 p] -> flds[p][swizzled c] ----
  const unsigned short* fb = feat + (long)b * CC * HWn;
#pragma unroll
  for (int s = 0; s < 3; ++s) {
    int j = tid + 256 * s;          // 0..767
    int c = j >> 3, pg = j & 7;
    bf16x8 v = *(const bf16x8*)(fb + (long)c * HWn + p0t + pg * 8);
    int c4 = c >> 3;                // 0..11
#pragma unroll
    for (int e = 0; e < 8; ++e) {
      int pl = pg * 8 + e;
      int kp = (pl ^ (pl >> 3)) & 7;
      flds[pl * 128 + ((c4 ^ kp) << 3) + (c & 7)] = (unsigned short)v[e];
    }
  }

  // ---- A fragments: w[o][c], kept in registers ----
  int l  = tid & 63;
  int wv = tid >> 6;
  int lm = l & 15, lg = l >> 4;
  bf16x8 a[6][3];
#pragma unroll
  for (int mt = 0; mt < 6; ++mt)
#pragma unroll
    for (int kk = 0; kk < 3; ++kk)
      a[mt][kk] = *(const bf16x8*)(wbf + (mt * 16 + lm) * CC + kk * 32 + lg * 8);

  __syncthreads();

  // ---- MFMA main: 3 K-steps x 6 M-tiles ----
  f32x4 acc[6];
#pragma unroll
  for (int mt = 0; mt < 6; ++mt) acc[mt] = (f32x4){0.f, 0.f, 0.f, 0.f};

  int pl = wv * 16 + lm;
  int kp = (pl ^ (pl >> 3)) & 7;
#pragma unroll
  for (int kk = 0; kk < 3; ++kk) {
    int c4 = kk * 4 + lg;
    bf16x8 bfrag = *(const bf16x8*)(&flds[pl * 128 + ((c4 ^ kp) << 3)]);
#pragma unroll
    for (int mt = 0; mt < 6; ++mt)
      acc[mt] = __builtin_amdgcn_mfma_f32_16x16x32_bf16(a[mt][kk], bfrag, acc[mt], 0, 0, 0);
  }

  // ---- epilogue: store mixed (bf16) + fused stats ----
  unsigned short* mb = mixed + (long)b * CC * HWn + p0t + pl;
#pragma unroll
  for (int mt = 0; mt < 6; ++mt) {
#pragma unroll
    for (int r = 0; r < 4; ++r) {
      float v = acc[mt][r];
      int o = mt * 16 + lg * 4 + r;
      mb[(long)o * HWn] = f2bf(v);
      float s = v, q = v * v;
      s += __shfl_xor(s, 1); q += __shfl_xor(q, 1);
      s += __shfl_xor(s, 2); q += __shfl_xor(q, 2);
      s += __shfl_xor(s, 4); q += __shfl_xor(q, 4);
      s += __shfl_xor(s, 8); q += __shfl_xor(q, 8);
      if (lm == 0) { atomicAdd(&lsum[o], s); atomicAdd(&lsq[o], q); }
    }
  }
  __syncthreads();
  if (tid < CC) atomicAdd(&ssum[tid], lsum[tid]);
  else if (tid < 2 * CC) atomicAdd(&ssq[tid - CC], lsq[tid - CC]);
}

__global__ void k_finalize(const float* __restrict__ ssum,
                           const float* __restrict__ ssq,
                           float* __restrict__ meanv,
                           float* __restrict__ rstdv) {
  int o = threadIdx.x;
  if (o < CC) {
    float m = ssum[o] * (1.0f / NPIX);
    float v = ssq[o] * (1.0f / NPIX) - m * m;
    meanv[o] = m;
    rstdv[o] = 1.0f / sqrtf(v + EPSf);
  }
}

// ---------------- BN (affine=False) + exact GELU, bf16 in / f32 out --------
__global__ __launch_bounds__(256) void k_bngelu(const unsigned short* __restrict__ mixed,
                                                const float* __restrict__ meanv,
                                                const float* __restrict__ rstdv,
                                                float* __restrict__ out) {
  long e = ((long)blockIdx.x * 256 + threadIdx.x) * 8;
  int o = (int)((e / HWn) % CC);       // 12544 % 8 == 0 -> same plane
  float m = meanv[o], r = rstdv[o];
  bf16x8 v = *(const bf16x8*)(mixed + e);
  float4 g0, g1;
  float z;
  z = (bf2f((unsigned short)v[0]) - m) * r; g0.x = 0.5f * z * (1.0f + erff(z * 0.70710678f));
  z = (bf2f((unsigned short)v[1]) - m) * r; g0.y = 0.5f * z * (1.0f + erff(z * 0.70710678f));
  z = (bf2f((unsigned short)v[2]) - m) * r; g0.z = 0.5f * z * (1.0f + erff(z * 0.70710678f));
  z = (bf2f((unsigned short)v[3]) - m) * r; g0.w = 0.5f * z * (1.0f + erff(z * 0.70710678f));
  z = (bf2f((unsigned short)v[4]) - m) * r; g1.x = 0.5f * z * (1.0f + erff(z * 0.70710678f));
  z = (bf2f((unsigned short)v[5]) - m) * r; g1.y = 0.5f * z * (1.0f + erff(z * 0.70710678f));
  z = (bf2f((unsigned short)v[6]) - m) * r; g1.z = 0.5f * z * (1.0f + erff(z * 0.70710678f));
  z = (bf2f((unsigned short)v[7]) - m) * r; g1.w = 0.5f * z * (1.0f + erff(z * 0.70710678f));
  *(float4*)(out + e)     = g0;
  *(float4*)(out + e + 4) = g1;
}

extern "C" void kernel_launch(void* const* d_in, const int* in_sizes, int n_in,
                              void* d_out, int out_size, void* d_ws, size_t ws_size,
                              hipStream_t stream) {
  const float* hk   = (const float*)d_in[0];   // local_hk [96,1,7,7]
  const float* x    = (const float*)d_in[1];   // x [32,96,112,112]
  const float* wmix = (const float*)d_in[2];   // w_mix [96,96]
  const float* bmix = (const float*)d_in[3];   // b_mix [96] (cancels in BN)
  (void)bmix;
  float* out = (float*)d_out;

  char* ws = (char*)d_ws;
  float* stats = (float*)ws;                           // sum,ssq,mean,rstd [96] each
  unsigned short* wbf    = (unsigned short*)(ws + 2048);            // 18432 B
  unsigned short* featbf = (unsigned short*)(ws + 32768);           // 77,070,336 B
  unsigned short* mixedbf = (unsigned short*)(ws + 32768 + 77070336);

  hipMemsetAsync(stats, 0, 768, stream);       // zero sum+ssq each call

  k_prep<<<36, 256, 0, stream>>>(wmix, wbf);
  k_conv<<<768, 256, 0, stream>>>(x, hk, featbf);
  k_mix<<<6272, 256, 0, stream>>>(featbf, wbf, mixedbf, stats, stats + 96);
  k_finalize<<<1, 128, 0, stream>>>(stats, stats + 96, stats + 192, stats + 288);
  k_bngelu<<<18816, 256, 0, stream>>>(mixedbf, stats + 192, stats + 288, out);
}

// Round 6
// 215.479 us; speedup vs baseline: 6.6556x; 1.4445x over previous
//
#include <hip/hip_runtime.h>
#include <cstdint>
#include <cstddef>

#define CC   96
#define BB   32
#define HHn  112
#define WWn  112
#define HWn  (HHn*WWn)        // 12544
#define NPIX (BB*HWn)         // 401408
#define EPSf 1e-5f

typedef __attribute__((ext_vector_type(8))) short bf16x8;
typedef __attribute__((ext_vector_type(4))) float f32x4;

__device__ inline unsigned short f2bf(float f) {      // RNE f32 -> bf16
  unsigned u = __float_as_uint(f);
  return (unsigned short)((u + 0x7FFFu + ((u >> 16) & 1u)) >> 16);
}
__device__ inline float bf2f(unsigned short h) {
  return __uint_as_float(((unsigned)h) << 16);
}

// ---------------- w_mix f32[o][c] -> bf16[o][c] ----------------
__global__ __launch_bounds__(256) void k_prep(const float* __restrict__ w,
                                              unsigned short* __restrict__ wbf) {
  int i = blockIdx.x * 256 + threadIdx.x;
  if (i < CC * CC) wbf[i] = f2bf(w[i]);
}

// ---------------- depthwise 7x7 conv, streaming-row, bf16 output ----------
__global__ __launch_bounds__(256) void k_conv(const float* __restrict__ x,
                                              const float* __restrict__ hk,
                                              unsigned short* __restrict__ feat) {
  int tid = threadIdx.x;
  int wid = __builtin_amdgcn_readfirstlane(tid >> 6);
  int plane = __builtin_amdgcn_readfirstlane(blockIdx.x * 4 + wid);
  int c = plane % CC;
  const float* xp = x + (long)plane * HWn;
  unsigned short* fp = feat + (long)plane * HWn;

  float wk[49];
  const float* kc = hk + c * 49;
#pragma unroll
  for (int i = 0; i < 49; ++i)
    wk[i] = __uint_as_float(__builtin_amdgcn_readfirstlane(__float_as_uint(kc[i])));

  int lane = tid & 63;
  int q = lane >> 4;
  int s = lane & 15;
  bool active = (s < 14);
  int cb = active ? s * 8 : 0;
  int qb = q * 28;
  bool aok0 = active && (s > 0);
  bool dok0 = (s < 13);
  int offA = aok0 ? cb - 4 : cb;
  int offD = dok0 ? cb + 8 : cb;

  float acc[7][8];
#pragma unroll
  for (int i = 0; i < 7; ++i)
#pragma unroll
    for (int j = 0; j < 8; ++j) acc[i][j] = 0.f;

  for (int blk = 0; blk < 5; ++blk) {
#pragma unroll
    for (int ph = 0; ph < 7; ++ph) {
      int rr = blk * 7 + ph;
      int r = qb + rr - 3;
      bool vok = (rr < 34) && ((unsigned)r < (unsigned)HHn);
      int rc = r < 0 ? 0 : (r > HHn - 1 ? HHn - 1 : r);
      const float* row = xp + rc * WWn;
      float4 A  = *(const float4*)(row + offA);
      float4 Bv = *(const float4*)(row + cb);
      float4 Cv = *(const float4*)(row + cb + 4);
      float4 D  = *(const float4*)(row + offD);
      bool aok = vok && aok0;
      bool dok = vok && dok0;
      float win[15];
      win[0]  = 0.f;
      win[1]  = aok ? A.y : 0.f;
      win[2]  = aok ? A.z : 0.f;
      win[3]  = aok ? A.w : 0.f;
      win[4]  = vok ? Bv.x : 0.f;
      win[5]  = vok ? Bv.y : 0.f;
      win[6]  = vok ? Bv.z : 0.f;
      win[7]  = vok ? Bv.w : 0.f;
      win[8]  = vok ? Cv.x : 0.f;
      win[9]  = vok ? Cv.y : 0.f;
      win[10] = vok ? Cv.z : 0.f;
      win[11] = vok ? Cv.w : 0.f;
      win[12] = dok ? D.x : 0.f;
      win[13] = dok ? D.y : 0.f;
      win[14] = dok ? D.z : 0.f;

#pragma unroll
      for (int kh = 0; kh < 7; ++kh) {
        if (rr >= kh && rr - kh <= 27) {
          const int slot = ((ph - kh) % 7 + 7) % 7;
#pragma unroll
          for (int kw = 0; kw < 7; ++kw) {
            float wv = wk[kh * 7 + kw];
#pragma unroll
            for (int j = 0; j < 8; ++j)
              acc[slot][j] = fmaf(win[j + kw + 1], wv, acc[slot][j]);
          }
        }
      }

      if (rr >= 6 && rr < 34) {
        const int slot = (ph + 1) % 7;
        if (active) {
          unsigned short* orow = fp + (qb + rr - 6) * WWn + cb;
          uint4 pk;
          pk.x = (unsigned)f2bf(acc[slot][0]) | ((unsigned)f2bf(acc[slot][1]) << 16);
          pk.y = (unsigned)f2bf(acc[slot][2]) | ((unsigned)f2bf(acc[slot][3]) << 16);
          pk.z = (unsigned)f2bf(acc[slot][4]) | ((unsigned)f2bf(acc[slot][5]) << 16);
          pk.w = (unsigned)f2bf(acc[slot][6]) | ((unsigned)f2bf(acc[slot][7]) << 16);
          *(uint4*)orow = pk;
        }
#pragma unroll
        for (int j = 0; j < 8; ++j) acc[slot][j] = 0.f;
      }
    }
  }
}

// ------- MFMA 1x1 mix (bf16) + fused BN stats, 256 px/block -------
// Block = 256 pixels of one image, 4 waves; wave owns 4 n-subtiles of 16 px.
// 72 MFMA/wave (6 M-tiles x 3 K x 4 N). B staged in LDS with kp-XOR swizzle
// (conflict-free scatter-writes & frag reads). Epilogue: register-accumulated
// stats (one shfl-reduce per o-slot), acc->LDS transpose, cooperative uint4
// coalesced stores (512B/32 lanes).
__global__ __launch_bounds__(256, 2) void k_mix(const unsigned short* __restrict__ feat,
                                                const unsigned short* __restrict__ wbf,
                                                unsigned short* __restrict__ mixed,
                                                float* __restrict__ ssum,
                                                float* __restrict__ ssq) {
  __shared__ unsigned short flds[256 * 128];   // 64 KB; reused for out-transpose
  __shared__ float lsum[CC], lsq[CC];

  int tid = threadIdx.x;
  int bid = blockIdx.x;
  int b = bid / 49, tile = bid % 49;
  int p0 = tile * 256;

  if (tid < CC) { lsum[tid] = 0.f; lsq[tid] = 0.f; }

  const unsigned short* fb = feat + (long)b * CC * HWn + p0;
  int u   = (tid >> 3) & 7;        // c within group of 8
  int v   = tid & 7;               // pixel-group low
  int wv  = tid >> 6;              // wave 0..3
  int pgl = wv * 8 + v;            // pixel-group 0..31 (8 px each)

  // ---- stage: load 12 x bf16x8 (8 lanes x 16B = 128B segments) ----
  bf16x8 vals[12];
#pragma unroll
  for (int s = 0; s < 12; ++s) {
    int c = s * 8 + u;
    vals[s] = *(const bf16x8*)(fb + (long)c * HWn + pgl * 8);
  }
  // scatter-write transpose into LDS: flds[pl][ (c4^kp)*8 + (c&7) ]
#pragma unroll
  for (int s = 0; s < 12; ++s) {
#pragma unroll
    for (int e = 0; e < 8; ++e) {
      int pl = pgl * 8 + e;
      int kp = (pl ^ (pl >> 3)) & 7;
      flds[pl * 128 + ((s ^ kp) << 3) + u] = (unsigned short)vals[s][e];
    }
  }

  // ---- A fragments: w[o][c] rows, kept in registers ----
  int l = tid & 63;
  int lm = l & 15, lg = l >> 4;
  bf16x8 a[6][3];
#pragma unroll
  for (int mt = 0; mt < 6; ++mt)
#pragma unroll
    for (int kk = 0; kk < 3; ++kk)
      a[mt][kk] = *(const bf16x8*)(wbf + (mt * 16 + lm) * CC + kk * 32 + lg * 8);

  __syncthreads();

  // ---- MFMA main: 4 subtiles x 3 K-steps x 6 M-tiles ----
  f32x4 acc[6][4];
#pragma unroll
  for (int mt = 0; mt < 6; ++mt)
#pragma unroll
    for (int j = 0; j < 4; ++j) acc[mt][j] = (f32x4){0.f, 0.f, 0.f, 0.f};

#pragma unroll
  for (int j = 0; j < 4; ++j) {
    int pl = (wv * 4 + j) * 16 + lm;
    int kp = (pl ^ (pl >> 3)) & 7;
#pragma unroll
    for (int kk = 0; kk < 3; ++kk) {
      bf16x8 bfrag = *(const bf16x8*)(&flds[pl * 128 + (((kk * 4 + lg) ^ kp) << 3)]);
#pragma unroll
      for (int mt = 0; mt < 6; ++mt)
        acc[mt][j] = __builtin_amdgcn_mfma_f32_16x16x32_bf16(a[mt][kk], bfrag, acc[mt][j], 0, 0, 0);
    }
  }

  __syncthreads();   // staging reads complete; reuse flds as [o][px'] u16

  // ---- stats (on rounded values) + transpose-store into LDS ----
#pragma unroll
  for (int mt = 0; mt < 6; ++mt) {
#pragma unroll
    for (int r = 0; r < 4; ++r) {
      int o = mt * 16 + lg * 4 + r;          // (o>>2)&3 == lg
      float s = 0.f, q = 0.f;
#pragma unroll
      for (int j = 0; j < 4; ++j) {
        unsigned short h = f2bf(acc[mt][j][r]);
        float vv = bf2f(h);
        int px = (wv * 4 + j) * 16 + lm;
        flds[o * 256 + (px ^ (lg << 4))] = h;
        s += vv; q += vv * vv;
      }
      s += __shfl_xor(s, 1); q += __shfl_xor(q, 1);
      s += __shfl_xor(s, 2); q += __shfl_xor(q, 2);
      s += __shfl_xor(s, 4); q += __shfl_xor(q, 4);
      s += __shfl_xor(s, 8); q += __shfl_xor(q, 8);
      if (lm == 0) { atomicAdd(&lsum[o], s); atomicAdd(&lsq[o], q); }
    }
  }
  __syncthreads();

  // ---- cooperative coalesced store: 12 iters, 512B per 32 lanes ----
  unsigned short* mbase = mixed + (long)b * CC * HWn + p0;
  int o2 = tid >> 5;          // 0..7
  int pxg = tid & 31;         // 8-px group
#pragma unroll
  for (int i = 0; i < 12; ++i) {
    int o = i * 8 + o2;
    int key = (o >> 2) & 3;
    uint4 vv = *(const uint4*)(&flds[o * 256 + ((pxg * 8) ^ (key << 4))]);
    *(uint4*)(mbase + (long)o * HWn + pxg * 8) = vv;
  }

  // ---- one global atomic per o per block ----
  if (tid < CC) atomicAdd(&ssum[tid], lsum[tid]);
  else if (tid < 2 * CC) atomicAdd(&ssq[tid - CC], lsq[tid - CC]);
}

__global__ void k_finalize(const float* __restrict__ ssum,
                           const float* __restrict__ ssq,
                           float* __restrict__ meanv,
                           float* __restrict__ rstdv) {
  int o = threadIdx.x;
  if (o < CC) {
    float m = ssum[o] * (1.0f / NPIX);
    float v = ssq[o] * (1.0f / NPIX) - m * m;
    meanv[o] = m;
    rstdv[o] = 1.0f / sqrtf(v + EPSf);
  }
}

// ---------------- BN (affine=False) + exact GELU, bf16 in / f32 out --------
__global__ __launch_bounds__(256) void k_bngelu(const unsigned short* __restrict__ mixed,
                                                const float* __restrict__ meanv,
                                                const float* __restrict__ rstdv,
                                                float* __restrict__ out) {
  long e = ((long)blockIdx.x * 256 + threadIdx.x) * 8;
  int o = (int)((e / HWn) % CC);       // 12544 % 8 == 0 -> same plane
  float m = meanv[o], r = rstdv[o];
  bf16x8 v = *(const bf16x8*)(mixed + e);
  float4 g0, g1;
  float z;
  z = (bf2f((unsigned short)v[0]) - m) * r; g0.x = 0.5f * z * (1.0f + erff(z * 0.70710678f));
  z = (bf2f((unsigned short)v[1]) - m) * r; g0.y = 0.5f * z * (1.0f + erff(z * 0.70710678f));
  z = (bf2f((unsigned short)v[2]) - m) * r; g0.z = 0.5f * z * (1.0f + erff(z * 0.70710678f));
  z = (bf2f((unsigned short)v[3]) - m) * r; g0.w = 0.5f * z * (1.0f + erff(z * 0.70710678f));
  z = (bf2f((unsigned short)v[4]) - m) * r; g1.x = 0.5f * z * (1.0f + erff(z * 0.70710678f));
  z = (bf2f((unsigned short)v[5]) - m) * r; g1.y = 0.5f * z * (1.0f + erff(z * 0.70710678f));
  z = (bf2f((unsigned short)v[6]) - m) * r; g1.z = 0.5f * z * (1.0f + erff(z * 0.70710678f));
  z = (bf2f((unsigned short)v[7]) - m) * r; g1.w = 0.5f * z * (1.0f + erff(z * 0.70710678f));
  *(float4*)(out + e)     = g0;
  *(float4*)(out + e + 4) = g1;
}

extern "C" void kernel_launch(void* const* d_in, const int* in_sizes, int n_in,
                              void* d_out, int out_size, void* d_ws, size_t ws_size,
                              hipStream_t stream) {
  const float* hk   = (const float*)d_in[0];   // local_hk [96,1,7,7]
  const float* x    = (const float*)d_in[1];   // x [32,96,112,112]
  const float* wmix = (const float*)d_in[2];   // w_mix [96,96]
  const float* bmix = (const float*)d_in[3];   // b_mix [96] (cancels in BN)
  (void)bmix;
  float* out = (float*)d_out;

  char* ws = (char*)d_ws;
  float* stats = (float*)ws;                           // sum,ssq,mean,rstd [96] each
  unsigned short* wbf     = (unsigned short*)(ws + 2048);            // 18432 B
  unsigned short* featbf  = (unsigned short*)(ws + 32768);           // 77,070,336 B
  unsigned short* mixedbf = (unsigned short*)(ws + 32768 + 77070336);

  hipMemsetAsync(stats, 0, 768, stream);       // zero sum+ssq each call

  k_prep<<<36, 256, 0, stream>>>(wmix, wbf);
  k_conv<<<768, 256, 0, stream>>>(x, hk, featbf);
  k_mix<<<1568, 256, 0, stream>>>(featbf, wbf, mixedbf, stats, stats + 96);
  k_finalize<<<1, 128, 0, stream>>>(stats, stats + 96, stats + 192, stats + 288);
  k_bngelu<<<18816, 256, 0, stream>>>(mixedbf, stats + 192, stats + 288, out);
}

// Round 7
// 210.372 us; speedup vs baseline: 6.8171x; 1.0243x over previous
//
#include <hip/hip_runtime.h>
#include <cstdint>
#include <cstddef>

#define CC   96
#define BB   32
#define HHn  112
#define WWn  112
#define HWn  (HHn*WWn)        // 12544
#define NPIX (BB*HWn)         // 401408
#define EPSf 1e-5f

typedef __attribute__((ext_vector_type(8))) short bf16x8;
typedef __attribute__((ext_vector_type(4))) float f32x4;

__device__ inline unsigned short f2bf(float f) {      // RNE f32 -> bf16
  unsigned u = __float_as_uint(f);
  return (unsigned short)((u + 0x7FFFu + ((u >> 16) & 1u)) >> 16);
}
__device__ inline float bf2f(unsigned short h) {
  return __uint_as_float(((unsigned)h) << 16);
}

// ---------------- w_mix f32[o][c] -> bf16[o][c] ----------------
__global__ __launch_bounds__(256) void k_prep(const float* __restrict__ w,
                                              unsigned short* __restrict__ wbf) {
  int i = blockIdx.x * 256 + threadIdx.x;
  if (i < CC * CC) wbf[i] = f2bf(w[i]);
}

// ---------------- depthwise 7x7 conv, streaming-row, bf16 output ----------
// One block per (b,c) plane; each of the 4 waves owns a 28-row band.
// Lane = q*16+s: 8-wide (s<14 active) x 7-tall chunk; streams 13 input rows,
// fully unrolled. 7 output rows <-> 7 acc slots, all indices compile-time.
__global__ __launch_bounds__(256) void k_conv(const float* __restrict__ x,
                                              const float* __restrict__ hk,
                                              unsigned short* __restrict__ feat) {
  int tid = threadIdx.x;
  int wid = __builtin_amdgcn_readfirstlane(tid >> 6);       // band 0..3
  int plane = __builtin_amdgcn_readfirstlane(blockIdx.x);   // (b*C+c)
  int c = plane % CC;
  const float* xp = x + (long)plane * HWn;
  unsigned short* fp = feat + (long)plane * HWn;

  float wk[49];
  const float* kc = hk + c * 49;
#pragma unroll
  for (int i = 0; i < 49; ++i)
    wk[i] = __uint_as_float(__builtin_amdgcn_readfirstlane(__float_as_uint(kc[i])));

  int lane = tid & 63;
  int q = lane >> 4;              // 7-row subchunk within band
  int s = lane & 15;
  bool active = (s < 14);
  int cb = active ? s * 8 : 0;    // col base; window cols cb-3..cb+10
  int qb = wid * 28 + q * 7;      // first output row of this lane
  bool aok0 = active && (s > 0);
  bool dok0 = (s < 13);
  int offA = aok0 ? cb - 4 : cb;
  int offD = dok0 ? cb + 8 : cb;

  float acc[7][8];
#pragma unroll
  for (int i = 0; i < 7; ++i)
#pragma unroll
    for (int j = 0; j < 8; ++j) acc[i][j] = 0.f;

#pragma unroll
  for (int rr = 0; rr < 13; ++rr) {       // streamed input rows qb-3 .. qb+9
    int r = qb + rr - 3;
    bool vok = ((unsigned)r < (unsigned)HHn);
    int rc = r < 0 ? 0 : (r > HHn - 1 ? HHn - 1 : r);
    const float* row = xp + rc * WWn;
    float4 A  = *(const float4*)(row + offA);
    float4 Bv = *(const float4*)(row + cb);
    float4 Cv = *(const float4*)(row + cb + 4);
    float4 D  = *(const float4*)(row + offD);
    bool aok = vok && aok0;
    bool dok = vok && dok0;
    float win[15];
    win[0]  = 0.f;
    win[1]  = aok ? A.y : 0.f;
    win[2]  = aok ? A.z : 0.f;
    win[3]  = aok ? A.w : 0.f;
    win[4]  = vok ? Bv.x : 0.f;
    win[5]  = vok ? Bv.y : 0.f;
    win[6]  = vok ? Bv.z : 0.f;
    win[7]  = vok ? Bv.w : 0.f;
    win[8]  = vok ? Cv.x : 0.f;
    win[9]  = vok ? Cv.y : 0.f;
    win[10] = vok ? Cv.z : 0.f;
    win[11] = vok ? Cv.w : 0.f;
    win[12] = dok ? D.x : 0.f;
    win[13] = dok ? D.y : 0.f;
    win[14] = dok ? D.z : 0.f;

    // input row rr feeds output row o = rr-kh, slot = o (compile-time)
#pragma unroll
    for (int kh = 0; kh < 7; ++kh) {
      if (rr >= kh && rr - kh <= 6) {
        const int slot = rr - kh;
#pragma unroll
        for (int kw = 0; kw < 7; ++kw) {
          float wv = wk[kh * 7 + kw];
#pragma unroll
          for (int j = 0; j < 8; ++j)
            acc[slot][j] = fmaf(win[j + kw + 1], wv, acc[slot][j]);
        }
      }
    }

    if (rr >= 6) {                        // output row rr-6 complete
      const int slot = rr - 6;
      if (active) {
        unsigned short* orow = fp + (qb + slot) * WWn + cb;
        uint4 pk;
        pk.x = (unsigned)f2bf(acc[slot][0]) | ((unsigned)f2bf(acc[slot][1]) << 16);
        pk.y = (unsigned)f2bf(acc[slot][2]) | ((unsigned)f2bf(acc[slot][3]) << 16);
        pk.z = (unsigned)f2bf(acc[slot][4]) | ((unsigned)f2bf(acc[slot][5]) << 16);
        pk.w = (unsigned)f2bf(acc[slot][6]) | ((unsigned)f2bf(acc[slot][7]) << 16);
        *(uint4*)orow = pk;
      }
    }
  }
}

// ------- MFMA 1x1 mix (bf16) + fused BN stats, 256 px/block -------
__global__ __launch_bounds__(256, 2) void k_mix(const unsigned short* __restrict__ feat,
                                                const unsigned short* __restrict__ wbf,
                                                unsigned short* __restrict__ mixed,
                                                float* __restrict__ ssum,
                                                float* __restrict__ ssq) {
  __shared__ unsigned short flds[256 * 128];   // 64 KB; reused for out-transpose
  __shared__ float lsum[CC], lsq[CC];

  int tid = threadIdx.x;
  int bid = blockIdx.x;
  int b = bid / 49, tile = bid % 49;
  int p0 = tile * 256;

  if (tid < CC) { lsum[tid] = 0.f; lsq[tid] = 0.f; }

  const unsigned short* fb = feat + (long)b * CC * HWn + p0;
  int u   = (tid >> 3) & 7;        // c within group of 8
  int v   = tid & 7;               // pixel-group low
  int wv  = tid >> 6;              // wave 0..3
  int pgl = wv * 8 + v;            // pixel-group 0..31 (8 px each)

  bf16x8 vals[12];
#pragma unroll
  for (int s = 0; s < 12; ++s) {
    int c = s * 8 + u;
    vals[s] = *(const bf16x8*)(fb + (long)c * HWn + pgl * 8);
  }
#pragma unroll
  for (int s = 0; s < 12; ++s) {
#pragma unroll
    for (int e = 0; e < 8; ++e) {
      int pl = pgl * 8 + e;
      int kp = (pl ^ (pl >> 3)) & 7;
      flds[pl * 128 + ((s ^ kp) << 3) + u] = (unsigned short)vals[s][e];
    }
  }

  int l = tid & 63;
  int lm = l & 15, lg = l >> 4;
  bf16x8 a[6][3];
#pragma unroll
  for (int mt = 0; mt < 6; ++mt)
#pragma unroll
    for (int kk = 0; kk < 3; ++kk)
      a[mt][kk] = *(const bf16x8*)(wbf + (mt * 16 + lm) * CC + kk * 32 + lg * 8);

  __syncthreads();

  f32x4 acc[6][4];
#pragma unroll
  for (int mt = 0; mt < 6; ++mt)
#pragma unroll
    for (int j = 0; j < 4; ++j) acc[mt][j] = (f32x4){0.f, 0.f, 0.f, 0.f};

#pragma unroll
  for (int j = 0; j < 4; ++j) {
    int pl = (wv * 4 + j) * 16 + lm;
    int kp = (pl ^ (pl >> 3)) & 7;
#pragma unroll
    for (int kk = 0; kk < 3; ++kk) {
      bf16x8 bfrag = *(const bf16x8*)(&flds[pl * 128 + (((kk * 4 + lg) ^ kp) << 3)]);
#pragma unroll
      for (int mt = 0; mt < 6; ++mt)
        acc[mt][j] = __builtin_amdgcn_mfma_f32_16x16x32_bf16(a[mt][kk], bfrag, acc[mt][j], 0, 0, 0);
    }
  }

  __syncthreads();   // staging reads complete; reuse flds as [o][px'] u16

#pragma unroll
  for (int mt = 0; mt < 6; ++mt) {
#pragma unroll
    for (int r = 0; r < 4; ++r) {
      int o = mt * 16 + lg * 4 + r;          // (o>>2)&3 == lg
      float s = 0.f, q = 0.f;
#pragma unroll
      for (int j = 0; j < 4; ++j) {
        unsigned short h = f2bf(acc[mt][j][r]);
        float vv = bf2f(h);
        int px = (wv * 4 + j) * 16 + lm;
        flds[o * 256 + (px ^ (lg << 4))] = h;
        s += vv; q += vv * vv;
      }
      s += __shfl_xor(s, 1); q += __shfl_xor(q, 1);
      s += __shfl_xor(s, 2); q += __shfl_xor(q, 2);
      s += __shfl_xor(s, 4); q += __shfl_xor(q, 4);
      s += __shfl_xor(s, 8); q += __shfl_xor(q, 8);
      if (lm == 0) { atomicAdd(&lsum[o], s); atomicAdd(&lsq[o], q); }
    }
  }
  __syncthreads();

  unsigned short* mbase = mixed + (long)b * CC * HWn + p0;
  int o2 = tid >> 5;          // 0..7
  int pxg = tid & 31;         // 8-px group
#pragma unroll
  for (int i = 0; i < 12; ++i) {
    int o = i * 8 + o2;
    int key = (o >> 2) & 3;
    uint4 vv = *(const uint4*)(&flds[o * 256 + ((pxg * 8) ^ (key << 4))]);
    *(uint4*)(mbase + (long)o * HWn + pxg * 8) = vv;
  }

  if (tid < CC) atomicAdd(&ssum[tid], lsum[tid]);
  else if (tid < 2 * CC) atomicAdd(&ssq[tid - CC], lsq[tid - CC]);
}

__global__ void k_finalize(const float* __restrict__ ssum,
                           const float* __restrict__ ssq,
                           float* __restrict__ meanv,
                           float* __restrict__ rstdv) {
  int o = threadIdx.x;
  if (o < CC) {
    float m = ssum[o] * (1.0f / NPIX);
    float v = ssq[o] * (1.0f / NPIX) - m * m;
    meanv[o] = m;
    rstdv[o] = 1.0f / sqrtf(v + EPSf);
  }
}

// ---------------- BN (affine=False) + exact GELU, bf16 in / f32 out --------
__global__ __launch_bounds__(256) void k_bngelu(const unsigned short* __restrict__ mixed,
                                                const float* __restrict__ meanv,
                                                const float* __restrict__ rstdv,
                                                float* __restrict__ out) {
  long e = ((long)blockIdx.x * 256 + threadIdx.x) * 8;
  int o = (int)((e / HWn) % CC);       // 12544 % 8 == 0 -> same plane
  float m = meanv[o], r = rstdv[o];
  bf16x8 v = *(const bf16x8*)(mixed + e);
  float4 g0, g1;
  float z;
  z = (bf2f((unsigned short)v[0]) - m) * r; g0.x = 0.5f * z * (1.0f + erff(z * 0.70710678f));
  z = (bf2f((unsigned short)v[1]) - m) * r; g0.y = 0.5f * z * (1.0f + erff(z * 0.70710678f));
  z = (bf2f((unsigned short)v[2]) - m) * r; g0.z = 0.5f * z * (1.0f + erff(z * 0.70710678f));
  z = (bf2f((unsigned short)v[3]) - m) * r; g0.w = 0.5f * z * (1.0f + erff(z * 0.70710678f));
  z = (bf2f((unsigned short)v[4]) - m) * r; g1.x = 0.5f * z * (1.0f + erff(z * 0.70710678f));
  z = (bf2f((unsigned short)v[5]) - m) * r; g1.y = 0.5f * z * (1.0f + erff(z * 0.70710678f));
  z = (bf2f((unsigned short)v[6]) - m) * r; g1.z = 0.5f * z * (1.0f + erff(z * 0.70710678f));
  z = (bf2f((unsigned short)v[7]) - m) * r; g1.w = 0.5f * z * (1.0f + erff(z * 0.70710678f));
  *(float4*)(out + e)     = g0;
  *(float4*)(out + e + 4) = g1;
}

extern "C" void kernel_launch(void* const* d_in, const int* in_sizes, int n_in,
                              void* d_out, int out_size, void* d_ws, size_t ws_size,
                              hipStream_t stream) {
  const float* hk   = (const float*)d_in[0];   // local_hk [96,1,7,7]
  const float* x    = (const float*)d_in[1];   // x [32,96,112,112]
  const float* wmix = (const float*)d_in[2];   // w_mix [96,96]
  const float* bmix = (const float*)d_in[3];   // b_mix [96] (cancels in BN)
  (void)bmix;
  float* out = (float*)d_out;

  char* ws = (char*)d_ws;
  float* stats = (float*)ws;                           // sum,ssq,mean,rstd [96] each
  unsigned short* wbf     = (unsigned short*)(ws + 2048);            // 18432 B
  unsigned short* featbf  = (unsigned short*)(ws + 32768);           // 77,070,336 B
  unsigned short* mixedbf = (unsigned short*)(ws + 32768 + 77070336);

  hipMemsetAsync(stats, 0, 768, stream);       // zero sum+ssq each call

  k_prep<<<36, 256, 0, stream>>>(wmix, wbf);
  k_conv<<<3072, 256, 0, stream>>>(x, hk, featbf);
  k_mix<<<1568, 256, 0, stream>>>(featbf, wbf, mixedbf, stats, stats + 96);
  k_finalize<<<1, 128, 0, stream>>>(stats, stats + 96, stats + 192, stats + 288);
  k_bngelu<<<18816, 256, 0, stream>>>(mixedbf, stats + 192, stats + 288, out);
}

// Round 8
// 193.124 us; speedup vs baseline: 7.4260x; 1.0893x over previous
//
#include <hip/hip_runtime.h>
#include <cstdint>
#include <cstddef>

#define CC   96
#define BB   32
#define HHn  112
#define WWn  112
#define HWn  (HHn*WWn)        // 12544
#define NPIX (BB*HWn)         // 401408
#define EPSf 1e-5f

typedef __attribute__((ext_vector_type(8))) short bf16x8;
typedef __attribute__((ext_vector_type(4))) float f32x4;

__device__ inline unsigned short f2bf(float f) {      // RNE f32 -> bf16
  unsigned u = __float_as_uint(f);
  return (unsigned short)((u + 0x7FFFu + ((u >> 16) & 1u)) >> 16);
}
__device__ inline float bf2f(unsigned short h) {
  return __uint_as_float(((unsigned)h) << 16);
}

// ---------------- w_mix f32[o][c] -> bf16[o][c] ----------------
__global__ __launch_bounds__(256) void k_prep(const float* __restrict__ w,
                                              unsigned short* __restrict__ wbf) {
  int i = blockIdx.x * 256 + threadIdx.x;
  if (i < CC * CC) wbf[i] = f2bf(w[i]);
}

// ---------------- depthwise 7x7 conv, LDS-staged plane ----------
// One block per (b,c) plane. Stage the full 112x112 f32 plane into LDS
// (coalesced float4 reg-staging, 13 iters), then each of the 4 waves computes
// a 28-row band; lane = q*16+s owns an 8-wide x 7-tall chunk reading rows via
// ds_read_b128 (latency hidden under ~420 cyc FMA per row-step).
__global__ __launch_bounds__(256) void k_conv(const float* __restrict__ x,
                                              const float* __restrict__ hk,
                                              unsigned short* __restrict__ feat) {
  __shared__ float lplane[HWn];          // 50,176 B

  int tid = threadIdx.x;
  int wid = __builtin_amdgcn_readfirstlane(tid >> 6);       // band 0..3
  int plane = __builtin_amdgcn_readfirstlane(blockIdx.x);   // (b*C+c)
  int c = plane % CC;
  const float* xp = x + (long)plane * HWn;
  unsigned short* fp = feat + (long)plane * HWn;

  // ---- stage plane -> LDS (12 full iters + 1 wave0 iter = 12544 floats) ----
#pragma unroll
  for (int it = 0; it < 12; ++it) {
    float4 v = *(const float4*)(xp + it * 1024 + tid * 4);
    *(float4*)(&lplane[it * 1024 + tid * 4]) = v;
  }
  if (tid < 64) {
    float4 v = *(const float4*)(xp + 12288 + tid * 4);
    *(float4*)(&lplane[12288 + tid * 4]) = v;
  }

  // 49 weights -> SGPRs (uniform per wave)
  float wk[49];
  const float* kc = hk + c * 49;
#pragma unroll
  for (int i = 0; i < 49; ++i)
    wk[i] = __uint_as_float(__builtin_amdgcn_readfirstlane(__float_as_uint(kc[i])));

  int lane = tid & 63;
  int q = lane >> 4;              // 7-row subchunk within band
  int s = lane & 15;
  bool active = (s < 14);
  int cb = active ? s * 8 : 0;    // col base; window cols cb-3..cb+10
  int qb = wid * 28 + q * 7;      // first output row of this lane
  bool aok0 = active && (s > 0);
  bool dok0 = (s < 13);
  int offA = aok0 ? cb - 4 : cb;
  int offD = dok0 ? cb + 8 : cb;

  float acc[7][8];
#pragma unroll
  for (int i = 0; i < 7; ++i)
#pragma unroll
    for (int j = 0; j < 8; ++j) acc[i][j] = 0.f;

  __syncthreads();

#pragma unroll
  for (int rr = 0; rr < 13; ++rr) {       // streamed input rows qb-3 .. qb+9
    int r = qb + rr - 3;
    bool vok = ((unsigned)r < (unsigned)HHn);
    int rc = r < 0 ? 0 : (r > HHn - 1 ? HHn - 1 : r);
    const float* row = &lplane[rc * WWn];
    float4 A  = *(const float4*)(row + offA);
    float4 Bv = *(const float4*)(row + cb);
    float4 Cv = *(const float4*)(row + cb + 4);
    float4 D  = *(const float4*)(row + offD);
    bool aok = vok && aok0;
    bool dok = vok && dok0;
    float win[15];
    win[0]  = 0.f;
    win[1]  = aok ? A.y : 0.f;
    win[2]  = aok ? A.z : 0.f;
    win[3]  = aok ? A.w : 0.f;
    win[4]  = vok ? Bv.x : 0.f;
    win[5]  = vok ? Bv.y : 0.f;
    win[6]  = vok ? Bv.z : 0.f;
    win[7]  = vok ? Bv.w : 0.f;
    win[8]  = vok ? Cv.x : 0.f;
    win[9]  = vok ? Cv.y : 0.f;
    win[10] = vok ? Cv.z : 0.f;
    win[11] = vok ? Cv.w : 0.f;
    win[12] = dok ? D.x : 0.f;
    win[13] = dok ? D.y : 0.f;
    win[14] = dok ? D.z : 0.f;

    // input row rr feeds output row o = rr-kh, slot = o (compile-time)
#pragma unroll
    for (int kh = 0; kh < 7; ++kh) {
      if (rr >= kh && rr - kh <= 6) {
        const int slot = rr - kh;
#pragma unroll
        for (int kw = 0; kw < 7; ++kw) {
          float wv = wk[kh * 7 + kw];
#pragma unroll
          for (int j = 0; j < 8; ++j)
            acc[slot][j] = fmaf(win[j + kw + 1], wv, acc[slot][j]);
        }
      }
    }

    if (rr >= 6) {                        // output row rr-6 complete
      const int slot = rr - 6;
      if (active) {
        unsigned short* orow = fp + (qb + slot) * WWn + cb;
        uint4 pk;
        pk.x = (unsigned)f2bf(acc[slot][0]) | ((unsigned)f2bf(acc[slot][1]) << 16);
        pk.y = (unsigned)f2bf(acc[slot][2]) | ((unsigned)f2bf(acc[slot][3]) << 16);
        pk.z = (unsigned)f2bf(acc[slot][4]) | ((unsigned)f2bf(acc[slot][5]) << 16);
        pk.w = (unsigned)f2bf(acc[slot][6]) | ((unsigned)f2bf(acc[slot][7]) << 16);
        *(uint4*)orow = pk;
      }
    }
  }
}

// ------- MFMA 1x1 mix (bf16) + fused BN stats, 256 px/block -------
__global__ __launch_bounds__(256, 2) void k_mix(const unsigned short* __restrict__ feat,
                                                const unsigned short* __restrict__ wbf,
                                                unsigned short* __restrict__ mixed,
                                                float* __restrict__ ssum,
                                                float* __restrict__ ssq) {
  __shared__ unsigned short flds[256 * 128];   // 64 KB; reused for out-transpose
  __shared__ float lsum[CC], lsq[CC];

  int tid = threadIdx.x;
  int bid = blockIdx.x;
  int b = bid / 49, tile = bid % 49;
  int p0 = tile * 256;

  if (tid < CC) { lsum[tid] = 0.f; lsq[tid] = 0.f; }

  const unsigned short* fb = feat + (long)b * CC * HWn + p0;
  int u   = (tid >> 3) & 7;        // c within group of 8
  int v   = tid & 7;               // pixel-group low
  int wv  = tid >> 6;              // wave 0..3
  int pgl = wv * 8 + v;            // pixel-group 0..31 (8 px each)

  bf16x8 vals[12];
#pragma unroll
  for (int s = 0; s < 12; ++s) {
    int c = s * 8 + u;
    vals[s] = *(const bf16x8*)(fb + (long)c * HWn + pgl * 8);
  }
#pragma unroll
  for (int s = 0; s < 12; ++s) {
#pragma unroll
    for (int e = 0; e < 8; ++e) {
      int pl = pgl * 8 + e;
      int kp = (pl ^ (pl >> 3)) & 7;
      flds[pl * 128 + ((s ^ kp) << 3) + u] = (unsigned short)vals[s][e];
    }
  }

  int l = tid & 63;
  int lm = l & 15, lg = l >> 4;
  bf16x8 a[6][3];
#pragma unroll
  for (int mt = 0; mt < 6; ++mt)
#pragma unroll
    for (int kk = 0; kk < 3; ++kk)
      a[mt][kk] = *(const bf16x8*)(wbf + (mt * 16 + lm) * CC + kk * 32 + lg * 8);

  __syncthreads();

  f32x4 acc[6][4];
#pragma unroll
  for (int mt = 0; mt < 6; ++mt)
#pragma unroll
    for (int j = 0; j < 4; ++j) acc[mt][j] = (f32x4){0.f, 0.f, 0.f, 0.f};

#pragma unroll
  for (int j = 0; j < 4; ++j) {
    int pl = (wv * 4 + j) * 16 + lm;
    int kp = (pl ^ (pl >> 3)) & 7;
#pragma unroll
    for (int kk = 0; kk < 3; ++kk) {
      bf16x8 bfrag = *(const bf16x8*)(&flds[pl * 128 + (((kk * 4 + lg) ^ kp) << 3)]);
#pragma unroll
      for (int mt = 0; mt < 6; ++mt)
        acc[mt][j] = __builtin_amdgcn_mfma_f32_16x16x32_bf16(a[mt][kk], bfrag, acc[mt][j], 0, 0, 0);
    }
  }

  __syncthreads();   // staging reads complete; reuse flds as [o][px'] u16

#pragma unroll
  for (int mt = 0; mt < 6; ++mt) {
#pragma unroll
    for (int r = 0; r < 4; ++r) {
      int o = mt * 16 + lg * 4 + r;          // (o>>2)&3 == lg
      float s = 0.f, q = 0.f;
#pragma unroll
      for (int j = 0; j < 4; ++j) {
        unsigned short h = f2bf(acc[mt][j][r]);
        float vv = bf2f(h);
        int px = (wv * 4 + j) * 16 + lm;
        flds[o * 256 + (px ^ (lg << 4))] = h;
        s += vv; q += vv * vv;
      }
      s += __shfl_xor(s, 1); q += __shfl_xor(q, 1);
      s += __shfl_xor(s, 2); q += __shfl_xor(q, 2);
      s += __shfl_xor(s, 4); q += __shfl_xor(q, 4);
      s += __shfl_xor(s, 8); q += __shfl_xor(q, 8);
      if (lm == 0) { atomicAdd(&lsum[o], s); atomicAdd(&lsq[o], q); }
    }
  }
  __syncthreads();

  unsigned short* mbase = mixed + (long)b * CC * HWn + p0;
  int o2 = tid >> 5;          // 0..7
  int pxg = tid & 31;         // 8-px group
#pragma unroll
  for (int i = 0; i < 12; ++i) {
    int o = i * 8 + o2;
    int key = (o >> 2) & 3;
    uint4 vv = *(const uint4*)(&flds[o * 256 + ((pxg * 8) ^ (key << 4))]);
    *(uint4*)(mbase + (long)o * HWn + pxg * 8) = vv;
  }

  if (tid < CC) atomicAdd(&ssum[tid], lsum[tid]);
  else if (tid < 2 * CC) atomicAdd(&ssq[tid - CC], lsq[tid - CC]);
}

__global__ void k_finalize(const float* __restrict__ ssum,
                           const float* __restrict__ ssq,
                           float* __restrict__ meanv,
                           float* __restrict__ rstdv) {
  int o = threadIdx.x;
  if (o < CC) {
    float m = ssum[o] * (1.0f / NPIX);
    float v = ssq[o] * (1.0f / NPIX) - m * m;
    meanv[o] = m;
    rstdv[o] = 1.0f / sqrtf(v + EPSf);
  }
}

// ---------------- BN (affine=False) + exact GELU, bf16 in / f32 out --------
__global__ __launch_bounds__(256) void k_bngelu(const unsigned short* __restrict__ mixed,
                                                const float* __restrict__ meanv,
                                                const float* __restrict__ rstdv,
                                                float* __restrict__ out) {
  long e = ((long)blockIdx.x * 256 + threadIdx.x) * 8;
  int o = (int)((e / HWn) % CC);       // 12544 % 8 == 0 -> same plane
  float m = meanv[o], r = rstdv[o];
  bf16x8 v = *(const bf16x8*)(mixed + e);
  float4 g0, g1;
  float z;
  z = (bf2f((unsigned short)v[0]) - m) * r; g0.x = 0.5f * z * (1.0f + erff(z * 0.70710678f));
  z = (bf2f((unsigned short)v[1]) - m) * r; g0.y = 0.5f * z * (1.0f + erff(z * 0.70710678f));
  z = (bf2f((unsigned short)v[2]) - m) * r; g0.z = 0.5f * z * (1.0f + erff(z * 0.70710678f));
  z = (bf2f((unsigned short)v[3]) - m) * r; g0.w = 0.5f * z * (1.0f + erff(z * 0.70710678f));
  z = (bf2f((unsigned short)v[4]) - m) * r; g1.x = 0.5f * z * (1.0f + erff(z * 0.70710678f));
  z = (bf2f((unsigned short)v[5]) - m) * r; g1.y = 0.5f * z * (1.0f + erff(z * 0.70710678f));
  z = (bf2f((unsigned short)v[6]) - m) * r; g1.z = 0.5f * z * (1.0f + erff(z * 0.70710678f));
  z = (bf2f((unsigned short)v[7]) - m) * r; g1.w = 0.5f * z * (1.0f + erff(z * 0.70710678f));
  *(float4*)(out + e)     = g0;
  *(float4*)(out + e + 4) = g1;
}

extern "C" void kernel_launch(void* const* d_in, const int* in_sizes, int n_in,
                              void* d_out, int out_size, void* d_ws, size_t ws_size,
                              hipStream_t stream) {
  const float* hk   = (const float*)d_in[0];   // local_hk [96,1,7,7]
  const float* x    = (const float*)d_in[1];   // x [32,96,112,112]
  const float* wmix = (const float*)d_in[2];   // w_mix [96,96]
  const float* bmix = (const float*)d_in[3];   // b_mix [96] (cancels in BN)
  (void)bmix;
  float* out = (float*)d_out;

  char* ws = (char*)d_ws;
  float* stats = (float*)ws;                           // sum,ssq,mean,rstd [96] each
  unsigned short* wbf     = (unsigned short*)(ws + 2048);            // 18432 B
  unsigned short* featbf  = (unsigned short*)(ws + 32768);           // 77,070,336 B
  unsigned short* mixedbf = (unsigned short*)(ws + 32768 + 77070336);

  hipMemsetAsync(stats, 0, 768, stream);       // zero sum+ssq each call

  k_prep<<<36, 256, 0, stream>>>(wmix, wbf);
  k_conv<<<3072, 256, 0, stream>>>(x, hk, featbf);
  k_mix<<<1568, 256, 0, stream>>>(featbf, wbf, mixedbf, stats, stats + 96);
  k_finalize<<<1, 128, 0, stream>>>(stats, stats + 96, stats + 192, stats + 288);
  k_bngelu<<<18816, 256, 0, stream>>>(mixedbf, stats + 192, stats + 288, out);
}

// Round 9
// 187.396 us; speedup vs baseline: 7.6530x; 1.0306x over previous
//
#include <hip/hip_runtime.h>
#include <cstdint>
#include <cstddef>

#define CC   96
#define BB   32
#define HHn  112
#define WWn  112
#define HWn  (HHn*WWn)        // 12544
#define NPIX (BB*HWn)         // 401408
#define EPSf 1e-5f

typedef __attribute__((ext_vector_type(8))) short bf16x8;
typedef __attribute__((ext_vector_type(4))) float f32x4;

__device__ inline unsigned short f2bf(float f) {      // RNE f32 -> bf16
  unsigned u = __float_as_uint(f);
  return (unsigned short)((u + 0x7FFFu + ((u >> 16) & 1u)) >> 16);
}
__device__ inline float bf2f(unsigned short h) {
  return __uint_as_float(((unsigned)h) << 16);
}

// ---------------- w_mix f32[o][c] -> bf16[o][c] ----------------
__global__ __launch_bounds__(256) void k_prep(const float* __restrict__ w,
                                              unsigned short* __restrict__ wbf) {
  int i = blockIdx.x * 256 + threadIdx.x;
  if (i < CC * CC) wbf[i] = f2bf(w[i]);
}

// ---------------- depthwise 7x7 conv, LDS-staged plane, 4px x 7row items ----
// One 512-thread block per (b,c) plane; f32 plane staged to LDS (coalesced).
// 448 active items: q = tid/28 (7-row chunk), s = tid%28 (4-col strip).
// acc[7][4] = 28 VGPRs; 3 ds_read_b128 per input row; launch_bounds(512,6)
// caps VGPR at 85 -> 24 waves/CU with 50 KB LDS (vs 12 before).
__global__ __launch_bounds__(512, 6) void k_conv(const float* __restrict__ x,
                                                 const float* __restrict__ hk,
                                                 unsigned short* __restrict__ feat) {
  __shared__ float lplane[HWn];          // 50,176 B

  int tid = threadIdx.x;
  int plane = __builtin_amdgcn_readfirstlane(blockIdx.x);   // (b*C+c)
  int c = plane % CC;
  const float* xp = x + (long)plane * HWn;
  unsigned short* fp = feat + (long)plane * HWn;

  // ---- stage plane -> LDS: 3136 float4 = 6*512 + 64 ----
#pragma unroll
  for (int it = 0; it < 6; ++it) {
    float4 v = *(const float4*)(xp + it * 2048 + tid * 4);
    *(float4*)(&lplane[it * 2048 + tid * 4]) = v;
  }
  if (tid < 64) {
    float4 v = *(const float4*)(xp + 12288 + tid * 4);
    *(float4*)(&lplane[12288 + tid * 4]) = v;
  }

  // 49 weights -> SGPRs (uniform per block)
  float wk[49];
  const float* kc = hk + c * 49;
#pragma unroll
  for (int i = 0; i < 49; ++i)
    wk[i] = __uint_as_float(__builtin_amdgcn_readfirstlane(__float_as_uint(kc[i])));

  int q = tid / 28;               // 7-row chunk 0..15 (tid<448)
  int s = tid % 28;               // 4-col strip 0..27
  int cb = s * 4;                 // col base; window cols cb-3..cb+6
  int qb = q * 7;                 // first output row
  bool aok0 = (s > 0);
  bool cok0 = (s < 27);
  int offA = aok0 ? cb - 4 : 0;
  int offC = cok0 ? cb + 4 : cb;

  float acc[7][4];
#pragma unroll
  for (int i = 0; i < 7; ++i)
#pragma unroll
    for (int j = 0; j < 4; ++j) acc[i][j] = 0.f;

  __syncthreads();

  if (tid < 448) {
#pragma unroll
    for (int rr = 0; rr < 13; ++rr) {     // input rows qb-3 .. qb+9
      int r = qb + rr - 3;
      bool vok = ((unsigned)r < (unsigned)HHn);
      int rc = r < 0 ? 0 : (r > HHn - 1 ? HHn - 1 : r);
      const float* row = &lplane[rc * WWn];
      float4 A  = *(const float4*)(row + offA);
      float4 Bv = *(const float4*)(row + cb);
      float4 Cv = *(const float4*)(row + offC);
      bool aok = vok && aok0;
      bool cok = vok && cok0;
      float win[10];                      // win[w] = x col cb-3+w
      win[0] = aok ? A.y : 0.f;
      win[1] = aok ? A.z : 0.f;
      win[2] = aok ? A.w : 0.f;
      win[3] = vok ? Bv.x : 0.f;
      win[4] = vok ? Bv.y : 0.f;
      win[5] = vok ? Bv.z : 0.f;
      win[6] = vok ? Bv.w : 0.f;
      win[7] = cok ? Cv.x : 0.f;
      win[8] = cok ? Cv.y : 0.f;
      win[9] = cok ? Cv.z : 0.f;

      // input row rr feeds output slot = rr-kh (compile-time indices)
#pragma unroll
      for (int kh = 0; kh < 7; ++kh) {
        if (rr >= kh && rr - kh <= 6) {
          const int slot = rr - kh;
#pragma unroll
          for (int kw = 0; kw < 7; ++kw) {
            float wv = wk[kh * 7 + kw];
#pragma unroll
            for (int j = 0; j < 4; ++j)
              acc[slot][j] = fmaf(win[j + kw], wv, acc[slot][j]);
          }
        }
      }

      if (rr >= 6) {                      // output row qb + rr-6 complete
        const int slot = rr - 6;
        unsigned short* orow = fp + (qb + slot) * WWn + cb;
        uint2 pk;
        pk.x = (unsigned)f2bf(acc[slot][0]) | ((unsigned)f2bf(acc[slot][1]) << 16);
        pk.y = (unsigned)f2bf(acc[slot][2]) | ((unsigned)f2bf(acc[slot][3]) << 16);
        *(uint2*)orow = pk;
      }
    }
  }
}

// ------- MFMA 1x1 mix (bf16) + fused BN stats, 256 px/block -------
__global__ __launch_bounds__(256, 2) void k_mix(const unsigned short* __restrict__ feat,
                                                const unsigned short* __restrict__ wbf,
                                                unsigned short* __restrict__ mixed,
                                                float* __restrict__ ssum,
                                                float* __restrict__ ssq) {
  __shared__ unsigned short flds[256 * 128];   // 64 KB; reused for out-transpose
  __shared__ float lsum[CC], lsq[CC];

  int tid = threadIdx.x;
  int bid = blockIdx.x;
  int b = bid / 49, tile = bid % 49;
  int p0 = tile * 256;

  if (tid < CC) { lsum[tid] = 0.f; lsq[tid] = 0.f; }

  const unsigned short* fb = feat + (long)b * CC * HWn + p0;
  int u   = (tid >> 3) & 7;        // c within group of 8
  int v   = tid & 7;               // pixel-group low
  int wv  = tid >> 6;              // wave 0..3
  int pgl = wv * 8 + v;            // pixel-group 0..31 (8 px each)

  bf16x8 vals[12];
#pragma unroll
  for (int s = 0; s < 12; ++s) {
    int c = s * 8 + u;
    vals[s] = *(const bf16x8*)(fb + (long)c * HWn + pgl * 8);
  }
#pragma unroll
  for (int s = 0; s < 12; ++s) {
#pragma unroll
    for (int e = 0; e < 8; ++e) {
      int pl = pgl * 8 + e;
      int kp = (pl ^ (pl >> 3)) & 7;
      flds[pl * 128 + ((s ^ kp) << 3) + u] = (unsigned short)vals[s][e];
    }
  }

  int l = tid & 63;
  int lm = l & 15, lg = l >> 4;
  bf16x8 a[6][3];
#pragma unroll
  for (int mt = 0; mt < 6; ++mt)
#pragma unroll
    for (int kk = 0; kk < 3; ++kk)
      a[mt][kk] = *(const bf16x8*)(wbf + (mt * 16 + lm) * CC + kk * 32 + lg * 8);

  __syncthreads();

  f32x4 acc[6][4];
#pragma unroll
  for (int mt = 0; mt < 6; ++mt)
#pragma unroll
    for (int j = 0; j < 4; ++j) acc[mt][j] = (f32x4){0.f, 0.f, 0.f, 0.f};

#pragma unroll
  for (int j = 0; j < 4; ++j) {
    int pl = (wv * 4 + j) * 16 + lm;
    int kp = (pl ^ (pl >> 3)) & 7;
#pragma unroll
    for (int kk = 0; kk < 3; ++kk) {
      bf16x8 bfrag = *(const bf16x8*)(&flds[pl * 128 + (((kk * 4 + lg) ^ kp) << 3)]);
#pragma unroll
      for (int mt = 0; mt < 6; ++mt)
        acc[mt][j] = __builtin_amdgcn_mfma_f32_16x16x32_bf16(a[mt][kk], bfrag, acc[mt][j], 0, 0, 0);
    }
  }

  __syncthreads();   // staging reads complete; reuse flds as [o][px'] u16

#pragma unroll
  for (int mt = 0; mt < 6; ++mt) {
#pragma unroll
    for (int r = 0; r < 4; ++r) {
      int o = mt * 16 + lg * 4 + r;          // (o>>2)&3 == lg
      float s = 0.f, q = 0.f;
#pragma unroll
      for (int j = 0; j < 4; ++j) {
        unsigned short h = f2bf(acc[mt][j][r]);
        float vv = bf2f(h);
        int px = (wv * 4 + j) * 16 + lm;
        flds[o * 256 + (px ^ (lg << 4))] = h;
        s += vv; q += vv * vv;
      }
      s += __shfl_xor(s, 1); q += __shfl_xor(q, 1);
      s += __shfl_xor(s, 2); q += __shfl_xor(q, 2);
      s += __shfl_xor(s, 4); q += __shfl_xor(q, 4);
      s += __shfl_xor(s, 8); q += __shfl_xor(q, 8);
      if (lm == 0) { atomicAdd(&lsum[o], s); atomicAdd(&lsq[o], q); }
    }
  }
  __syncthreads();

  unsigned short* mbase = mixed + (long)b * CC * HWn + p0;
  int o2 = tid >> 5;          // 0..7
  int pxg = tid & 31;         // 8-px group
#pragma unroll
  for (int i = 0; i < 12; ++i) {
    int o = i * 8 + o2;
    int key = (o >> 2) & 3;
    uint4 vv = *(const uint4*)(&flds[o * 256 + ((pxg * 8) ^ (key << 4))]);
    *(uint4*)(mbase + (long)o * HWn + pxg * 8) = vv;
  }

  if (tid < CC) atomicAdd(&ssum[tid], lsum[tid]);
  else if (tid < 2 * CC) atomicAdd(&ssq[tid - CC], lsq[tid - CC]);
}

__global__ void k_finalize(const float* __restrict__ ssum,
                           const float* __restrict__ ssq,
                           float* __restrict__ meanv,
                           float* __restrict__ rstdv) {
  int o = threadIdx.x;
  if (o < CC) {
    float m = ssum[o] * (1.0f / NPIX);
    float v = ssq[o] * (1.0f / NPIX) - m * m;
    meanv[o] = m;
    rstdv[o] = 1.0f / sqrtf(v + EPSf);
  }
}

// ---------------- BN (affine=False) + exact GELU, bf16 in / f32 out --------
__global__ __launch_bounds__(256) void k_bngelu(const unsigned short* __restrict__ mixed,
                                                const float* __restrict__ meanv,
                                                const float* __restrict__ rstdv,
                                                float* __restrict__ out) {
  long e = ((long)blockIdx.x * 256 + threadIdx.x) * 8;
  int o = (int)((e / HWn) % CC);       // 12544 % 8 == 0 -> same plane
  float m = meanv[o], r = rstdv[o];
  bf16x8 v = *(const bf16x8*)(mixed + e);
  float4 g0, g1;
  float z;
  z = (bf2f((unsigned short)v[0]) - m) * r; g0.x = 0.5f * z * (1.0f + erff(z * 0.70710678f));
  z = (bf2f((unsigned short)v[1]) - m) * r; g0.y = 0.5f * z * (1.0f + erff(z * 0.70710678f));
  z = (bf2f((unsigned short)v[2]) - m) * r; g0.z = 0.5f * z * (1.0f + erff(z * 0.70710678f));
  z = (bf2f((unsigned short)v[3]) - m) * r; g0.w = 0.5f * z * (1.0f + erff(z * 0.70710678f));
  z = (bf2f((unsigned short)v[4]) - m) * r; g1.x = 0.5f * z * (1.0f + erff(z * 0.70710678f));
  z = (bf2f((unsigned short)v[5]) - m) * r; g1.y = 0.5f * z * (1.0f + erff(z * 0.70710678f));
  z = (bf2f((unsigned short)v[6]) - m) * r; g1.z = 0.5f * z * (1.0f + erff(z * 0.70710678f));
  z = (bf2f((unsigned short)v[7]) - m) * r; g1.w = 0.5f * z * (1.0f + erff(z * 0.70710678f));
  *(float4*)(out + e)     = g0;
  *(float4*)(out + e + 4) = g1;
}

extern "C" void kernel_launch(void* const* d_in, const int* in_sizes, int n_in,
                              void* d_out, int out_size, void* d_ws, size_t ws_size,
                              hipStream_t stream) {
  const float* hk   = (const float*)d_in[0];   // local_hk [96,1,7,7]
  const float* x    = (const float*)d_in[1];   // x [32,96,112,112]
  const float* wmix = (const float*)d_in[2];   // w_mix [96,96]
  const float* bmix = (const float*)d_in[3];   // b_mix [96] (cancels in BN)
  (void)bmix;
  float* out = (float*)d_out;

  char* ws = (char*)d_ws;
  float* stats = (float*)ws;                           // sum,ssq,mean,rstd [96] each
  unsigned short* wbf     = (unsigned short*)(ws + 2048);            // 18432 B
  unsigned short* featbf  = (unsigned short*)(ws + 32768);           // 77,070,336 B
  unsigned short* mixedbf = (unsigned short*)(ws + 32768 + 77070336);

  hipMemsetAsync(stats, 0, 768, stream);       // zero sum+ssq each call

  k_prep<<<36, 256, 0, stream>>>(wmix, wbf);
  k_conv<<<3072, 512, 0, stream>>>(x, hk, featbf);
  k_mix<<<1568, 256, 0, stream>>>(featbf, wbf, mixedbf, stats, stats + 96);
  k_finalize<<<1, 128, 0, stream>>>(stats, stats + 96, stats + 192, stats + 288);
  k_bngelu<<<18816, 256, 0, stream>>>(mixedbf, stats + 192, stats + 288, out);
}